// Round 8
// baseline (1031.978 us; speedup 1.0000x reference)
//
#include <hip/hip_runtime.h>
#include <hip/hip_bf16.h>

// GIN: N=100000, E=1.6M, G=64, D=128, L=4.
// R8: fused per-layer kernel k_layer (64-node tile): gather writes the MFMA
// A-tile directly in LDS (no global round-trip), then dual-GEMM MLP with H1
// repack + W2 restage, BN stats + bf16 store in epilogue. One-time CSR build
// (partition + scan + per-bucket LDS counting sort). bnpool 4x wider grid.

#define N_NODES   100000
#define N_EDGES   1600000
#define N_GRAPHS  64
#define DIM       128
#define N_LAYERS  4
#define CLS_IN    640
#define CLS_HID   256
#define N_CLASSES 10
#define LRELU_SLOPE 0.01f
#define BN_EPS_F    1e-5f

#define NBUCK    782      // ceil(100000/128)   (CSR build granularity)
#define BUCK_CAP 4096
#define ECAP     1536     // per-64-node-tile LDS edge cap (avg 1024)

typedef __attribute__((ext_vector_type(8))) short bf16x8;
typedef __attribute__((ext_vector_type(4))) float f32x4;

__device__ __forceinline__ float lrelu(float x) { return x > 0.f ? x : LRELU_SLOPE * x; }

__device__ __forceinline__ ushort bf16r(float x) {
    uint a = __float_as_uint(x);
    return (ushort)((a + 0x7FFFu + ((a >> 16) & 1u)) >> 16);
}
__device__ __forceinline__ uint pack2(float x, float y) {
    uint a = __float_as_uint(x), b = __float_as_uint(y);
    a = (a + 0x7FFFu + ((a >> 16) & 1u)) >> 16;
    b = (b + 0x7FFFu + ((b >> 16) & 1u)) >> 16;
    return a | (b << 16);
}
__device__ __forceinline__ float2 unpack2(uint v) {
    return make_float2(__uint_as_float(v << 16), __uint_as_float(v & 0xFFFF0000u));
}

// ---------------- weight convert: W[k][n] fp32 -> Wt[n][k] bf16 ----------------
__global__ void k_convert_w(const float* __restrict__ W1, const float* __restrict__ W2,
                            ushort* __restrict__ W1t, ushort* __restrict__ W2t) {
    int gid = blockIdx.x * blockDim.x + threadIdx.x;   // 8 * 16384
    if (gid >= 8 * DIM * DIM) return;
    int mat = gid >> 14, idx = gid & 16383;
    int k = idx >> 7, n = idx & 127;
    const float* src = (mat < 4) ? (W1 + mat * DIM * DIM) : (W2 + (mat - 4) * DIM * DIM);
    ushort* dst = (mat < 4) ? (W1t + mat * DIM * DIM) : (W2t + (mat - 4) * DIM * DIM);
    dst[n * DIM + k] = bf16r(src[k * DIM + n]);
}

// ---------------- initial one-hot features (bf16, row-major) + zs[0] pooling ----------------
__global__ void k_build_x(const int* __restrict__ deg, const int* __restrict__ batch,
                          uint* __restrict__ x, float* __restrict__ pooled) {
    int gid = blockIdx.x * blockDim.x + threadIdx.x;   // one per uint (2 bf16)
    if (gid >= N_NODES * 64) return;
    int i = gid >> 6, c = gid & 63;
    int d = deg[i];
    uint v = 0;
    if ((d >> 1) == c) v = 0x3F80u << (16 * (d & 1));
    x[gid] = v;
    if (c == 0) atomicAdd(&pooled[batch[i] * CLS_IN + d], 1.0f);
}

// ---------------- bucketed edge partition ----------------
// bucket b = dst >> 7; packed = (dst&127)<<17 | src
__global__ void __launch_bounds__(1024) k_partition(const int* __restrict__ src,
                                                    const int* __restrict__ dst,
                                                    uint* __restrict__ cursor,
                                                    uint* __restrict__ ebuf) {
    __shared__ uint hist[NBUCK];
    __shared__ uint basev[NBUCK];
    int t = threadIdx.x;
    for (int b = t; b < NBUCK; b += 1024) hist[b] = 0;
    __syncthreads();
    int e0 = blockIdx.x * 16384;
    uint msrc[16], mdst[16], mrank[16];
#pragma unroll
    for (int i = 0; i < 16; ++i) {
        int e = e0 + i * 1024 + t;
        if (e < N_EDGES) {
            msrc[i] = (uint)src[e];
            mdst[i] = (uint)dst[e];
            mrank[i] = atomicAdd(&hist[mdst[i] >> 7], 1u);
        } else mdst[i] = 0xFFFFFFFFu;
    }
    __syncthreads();
    for (int b = t; b < NBUCK; b += 1024) {
        uint c = hist[b];
        basev[b] = c ? (uint)(b * BUCK_CAP) + atomicAdd(&cursor[b], c) : 0u;
    }
    __syncthreads();
#pragma unroll
    for (int i = 0; i < 16; ++i) {
        if (mdst[i] != 0xFFFFFFFFu) {
            uint b = mdst[i] >> 7;
            ebuf[basev[b] + mrank[i]] = ((mdst[i] & 127u) << 17) | msrc[i];
        }
    }
}

// ---------------- bucket base offsets (exclusive scan of counts) ----------------
__global__ void __launch_bounds__(1024) k_bases(const uint* __restrict__ cursor,
                                                uint* __restrict__ base,
                                                int* __restrict__ indptr) {
    __shared__ uint sh[1024];
    int t = threadIdx.x;
    uint v = (t < NBUCK) ? min(cursor[t], (uint)BUCK_CAP) : 0u;
    sh[t] = v; __syncthreads();
    for (int off = 1; off < 1024; off <<= 1) {
        uint add = (t >= off) ? sh[t - off] : 0u;
        __syncthreads();
        sh[t] += add;
        __syncthreads();
    }
    if (t < NBUCK) base[t] = sh[t] - v;          // exclusive
    if (t == NBUCK - 1) indptr[N_NODES] = (int)sh[t];
}

// ---------------- per-bucket LDS counting sort -> compacted CSR + indptr ----------------
__global__ void __launch_bounds__(512) k_sort(const uint* __restrict__ ebuf,
                                              const uint* __restrict__ cursor,
                                              const uint* __restrict__ base,
                                              int* __restrict__ csr,
                                              int* __restrict__ indptr) {
    __shared__ uint sortedL[BUCK_CAP];
    __shared__ uint hist[128];
    __shared__ uint startv[129];
    const int t = threadIdx.x, b = blockIdx.x;
    int cnt = (int)cursor[b]; if (cnt > BUCK_CAP) cnt = BUCK_CAP;
    if (t < 128) hist[t] = 0;
    __syncthreads();
    uint ent[8], rank[8];
    const uint* ep = ebuf + b * BUCK_CAP;
#pragma unroll
    for (int k = 0; k < 8; ++k) {
        int i = t + k * 512;
        if (i < cnt) { ent[k] = ep[i]; rank[k] = atomicAdd(&hist[ent[k] >> 17], 1u); }
    }
    __syncthreads();
    if (t < 128) startv[t + 1] = hist[t];
    if (t == 0) startv[0] = 0;
    __syncthreads();
    for (int off = 1; off < 128; off <<= 1) {
        uint add = (t < 128 && t >= off) ? startv[t + 1 - off] : 0u;
        __syncthreads();
        if (t < 128 && t >= off) startv[t + 1] += add;
        __syncthreads();
    }
#pragma unroll
    for (int k = 0; k < 8; ++k) {
        int i = t + k * 512;
        if (i < cnt) sortedL[startv[ent[k] >> 17] + rank[k]] = ent[k];
    }
    __syncthreads();
    int gbase = (int)base[b];
    for (int i = t; i < cnt; i += 512)
        csr[gbase + i] = (int)(sortedL[i] & 0x1FFFFu);
    if (t < 128) {
        int node = b * 128 + t;
        if (node < N_NODES) indptr[node] = gbase + (int)startv[t];
    }
}

// ---------------- fused layer: gather -> A-tile in LDS -> MLP -> C + BN stats ----------------
// 64-node tile, 256 threads. LDS: As[64][136]u16 | Ws[128][136]u16 (Cs[64][132]f32
// aliases Ws) | eL[1536] | sv[65]  ~= 58.7 KB -> 2 blocks/CU.
#define LYR_LDS (17408 + 34816 + ECAP * 4 + 272)
__global__ void __launch_bounds__(256) k_layer(const uint* __restrict__ h,
                                               const int* __restrict__ indptr,
                                               const int* __restrict__ csr,
                                               const ushort* __restrict__ W1t,
                                               const float* __restrict__ b1,
                                               const ushort* __restrict__ W2t,
                                               const float* __restrict__ b2,
                                               ushort* __restrict__ C,
                                               float* __restrict__ stats,
                                               const float* __restrict__ epsv, int layer) {
    __shared__ char pool[LYR_LDS];
    ushort* As = (ushort*)pool;                  // [64][136] bf16: A, then H1
    ushort* Ws = (ushort*)(pool + 17408);        // [128][136] bf16: W1t, then W2t
    float*  Cs = (float*)(pool + 17408);         // [64][132] fp32 (aliases Ws)
    int*    eL = (int*)(pool + 17408 + 34816);   // [ECAP]
    int*    sv = (int*)(pool + 17408 + 34816 + ECAP * 4);  // [65]
    const int t = threadIdx.x, lane = t & 63, wave = t >> 6;
    const int node0 = blockIdx.x * 64;
    if (t < 65) {
        int n = node0 + t;
        sv[t] = indptr[n > N_NODES ? N_NODES : n];
    }
    {   // stage W1 while indptr lands
        int rw = t >> 1, hh = t & 1;
        const uint4* gw = (const uint4*)(W1t + rw * DIM + hh * 64);
        uint4* lw = (uint4*)(Ws + rw * 136 + hh * 64);
#pragma unroll
        for (int k = 0; k < 8; ++k) lw[k] = gw[k];
    }
    __syncthreads();
    const int gbase = sv[0];
    {
        int cnt = sv[64] - gbase;
        int stg = cnt > ECAP ? ECAP : cnt;
        for (int i = t; i < stg; i += 256) eL[i] = csr[gbase + i];
    }
    __syncthreads();
    // ---- gather into As (wave owns 16 nodes) ----
    const float s = 1.0f + epsv[layer];
    for (int ri = 0; ri < 16; ++ri) {
        int r = wave * 16 + ri;
        int g = node0 + r;
        uint* Arow = (uint*)(As + r * 136);     // 16B-aligned (136*2 = 272)
        if (g >= N_NODES) { Arow[lane] = 0u; continue; }
        int beg = sv[r] - gbase, end = sv[r + 1] - gbase;
        float2 own = unpack2(h[g * 64 + lane]);
        float ax = s * own.x, ay = s * own.y;
        if (end <= ECAP) {
            int j = beg;
            for (; j + 4 <= end; j += 4) {
                int i0 = eL[j], i1 = eL[j + 1], i2 = eL[j + 2], i3 = eL[j + 3];
                uint w0 = h[i0 * 64 + lane], w1 = h[i1 * 64 + lane];
                uint w2 = h[i2 * 64 + lane], w3 = h[i3 * 64 + lane];
                float2 f0 = unpack2(w0), f1 = unpack2(w1), f2 = unpack2(w2), f3 = unpack2(w3);
                ax += (f0.x + f1.x) + (f2.x + f3.x);
                ay += (f0.y + f1.y) + (f2.y + f3.y);
            }
            for (; j < end; ++j) {
                float2 f = unpack2(h[eL[j] * 64 + lane]);
                ax += f.x; ay += f.y;
            }
        } else {   // overflow fallback (statistically never)
            for (int j = beg; j < end; ++j) {
                int u = csr[gbase + j];
                float2 f = unpack2(h[u * 64 + lane]);
                ax += f.x; ay += f.y;
            }
        }
        Arow[lane] = pack2(ax, ay);
    }
    __syncthreads();
    // ---- MFMA mapping: 4 waves, 32 rows x 64 cols each ----
    const int q = lane >> 4, m = lane & 15;
    const int R = (wave >> 1) * 32, Cb = (wave & 1) * 64;
    // ---- phase 1: H1 = lrelu(A @ W1 + b1) ----
    {
        f32x4 acc[2][4] = {};
#pragma unroll
        for (int ks = 0; ks < 4; ++ks) {
            bf16x8 a[2], b[4];
#pragma unroll
            for (int i = 0; i < 2; ++i)
                a[i] = *(const bf16x8*)(As + (R + i * 16 + m) * 136 + ks * 32 + q * 8);
#pragma unroll
            for (int j = 0; j < 4; ++j)
                b[j] = *(const bf16x8*)(Ws + (Cb + j * 16 + m) * 136 + ks * 32 + q * 8);
#pragma unroll
            for (int i = 0; i < 2; ++i)
#pragma unroll
                for (int j = 0; j < 4; ++j)
                    acc[i][j] = __builtin_amdgcn_mfma_f32_16x16x32_bf16(a[i], b[j], acc[i][j], 0, 0, 0);
        }
        __syncthreads();   // phase-1 LDS reads done
        float bias1[4];
#pragma unroll
        for (int j = 0; j < 4; ++j) bias1[j] = b1[Cb + j * 16 + m];
#pragma unroll
        for (int i = 0; i < 2; ++i)
#pragma unroll
            for (int j = 0; j < 4; ++j)
#pragma unroll
                for (int r = 0; r < 4; ++r)
                    As[(R + i * 16 + q * 4 + r) * 136 + Cb + j * 16 + m] =
                        bf16r(lrelu(acc[i][j][r] + bias1[j]));
        {   // restage Ws <- W2t
            int rw = t >> 1, hh = t & 1;
            const uint4* gw = (const uint4*)(W2t + rw * DIM + hh * 64);
            uint4* lw = (uint4*)(Ws + rw * 136 + hh * 64);
#pragma unroll
            for (int k = 0; k < 8; ++k) lw[k] = gw[k];
        }
    }
    __syncthreads();
    // ---- phase 2: C = H1 @ W2 + b2 ----
    f32x4 acc2[2][4] = {};
#pragma unroll
    for (int ks = 0; ks < 4; ++ks) {
        bf16x8 a[2], b[4];
#pragma unroll
        for (int i = 0; i < 2; ++i)
            a[i] = *(const bf16x8*)(As + (R + i * 16 + m) * 136 + ks * 32 + q * 8);
#pragma unroll
        for (int j = 0; j < 4; ++j)
            b[j] = *(const bf16x8*)(Ws + (Cb + j * 16 + m) * 136 + ks * 32 + q * 8);
#pragma unroll
        for (int i = 0; i < 2; ++i)
#pragma unroll
            for (int j = 0; j < 4; ++j)
                acc2[i][j] = __builtin_amdgcn_mfma_f32_16x16x32_bf16(a[i], b[j], acc2[i][j], 0, 0, 0);
    }
    __syncthreads();   // phase-2 LDS reads done; Cs may alias Ws now
    float bias2[4];
#pragma unroll
    for (int j = 0; j < 4; ++j) bias2[j] = b2[Cb + j * 16 + m];
#pragma unroll
    for (int i = 0; i < 2; ++i)
#pragma unroll
        for (int j = 0; j < 4; ++j)
#pragma unroll
            for (int r = 0; r < 4; ++r)
                Cs[(R + i * 16 + q * 4 + r) * 132 + Cb + j * 16 + m] = acc2[i][j][r] + bias2[j];
    __syncthreads();
    if (t < DIM) {   // BN stats (pre-activation sums)
        int rows = N_NODES - node0; if (rows > 64) rows = 64;
        float s1 = 0.f, s2 = 0.f;
        for (int r = 0; r < rows; ++r) { float v = Cs[r * 132 + t]; s1 += v; s2 += v * v; }
        atomicAdd(&stats[t], s1);
        atomicAdd(&stats[DIM + t], s2);
    }
    {   // bf16 pack + coalesced store (4 threads/row, 4 uint4 each)
        int r2 = t >> 2, c4 = t & 3;
        if (node0 + r2 < N_NODES) {
            uint4* outp = (uint4*)(C + (size_t)(node0 + r2) * DIM);
#pragma unroll
            for (int k = 0; k < 4; ++k) {
                int chunk = c4 * 4 + k;
                float4 v0 = *(const float4*)(Cs + r2 * 132 + chunk * 8);
                float4 v1 = *(const float4*)(Cs + r2 * 132 + chunk * 8 + 4);
                uint4 o;
                o.x = pack2(v0.x, v0.y); o.y = pack2(v0.z, v0.w);
                o.z = pack2(v1.x, v1.y); o.w = pack2(v1.z, v1.w);
                outp[chunk] = o;
            }
        }
    }
}

// ---------------- BN apply (inline finalize) + lrelu + fused pooling ----------------
#define PROWS 64
__global__ void __launch_bounds__(256) k_bnpool(const uint* __restrict__ src,
                                                uint* __restrict__ dst,
                                                const float* __restrict__ stats,
                                                const float* __restrict__ bn_g,
                                                const float* __restrict__ bn_b, int layer,
                                                const int* __restrict__ batch,
                                                float* __restrict__ pooled, int colOff) {
    int c = threadIdx.x & 63;
    int chunk = threadIdx.x >> 6;
    int r0 = blockIdx.x * PROWS + chunk * (PROWS / 4);
    float sc0, sh0, sc1, sh1;
    {
        int f0 = 2 * c, f1 = 2 * c + 1;
        float m0 = stats[f0] * (1.0f / N_NODES);
        float m1 = stats[f1] * (1.0f / N_NODES);
        float v0 = stats[DIM + f0] * (1.0f / N_NODES) - m0 * m0;
        float v1 = stats[DIM + f1] * (1.0f / N_NODES) - m1 * m1;
        sc0 = bn_g[layer * DIM + f0] * rsqrtf(v0 + BN_EPS_F);
        sc1 = bn_g[layer * DIM + f1] * rsqrtf(v1 + BN_EPS_F);
        sh0 = bn_b[layer * DIM + f0] - m0 * sc0;
        sh1 = bn_b[layer * DIM + f1] - m1 * sc1;
    }
    int curg = -1;
    float a0 = 0.f, a1 = 0.f;
    for (int i = 0; i < PROWS / 4; ++i) {
        int r = r0 + i;
        if (r >= N_NODES) break;
        float2 v = unpack2(src[r * 64 + c]);
        float x0 = lrelu(v.x * sc0 + sh0);
        float x1 = lrelu(v.y * sc1 + sh1);
        dst[r * 64 + c] = pack2(x0, x1);
        int g = batch[r];
        if (g != curg) {
            if (curg >= 0) {
                atomicAdd(&pooled[curg * CLS_IN + colOff + 2 * c], a0);
                atomicAdd(&pooled[curg * CLS_IN + colOff + 2 * c + 1], a1);
            }
            curg = g; a0 = 0.f; a1 = 0.f;
        }
        a0 += x0; a1 += x1;
    }
    if (curg >= 0) {
        atomicAdd(&pooled[curg * CLS_IN + colOff + 2 * c], a0);
        atomicAdd(&pooled[curg * CLS_IN + colOff + 2 * c + 1], a1);
    }
}

// ---------------- classifier head (fp32): one block per graph ----------------
__global__ void __launch_bounds__(256) k_classifier(const float* __restrict__ pooled,
                                                    const float* __restrict__ Wc1,
                                                    const float* __restrict__ bc1,
                                                    const float* __restrict__ Wc2,
                                                    const float* __restrict__ bc2,
                                                    float* __restrict__ out) {
    __shared__ float p[CLS_IN];
    __shared__ float hh[CLS_HID];
    int g = blockIdx.x, t = threadIdx.x;
    for (int j = t; j < CLS_IN; j += 256) p[j] = lrelu(pooled[g * CLS_IN + j]);
    __syncthreads();
    float acc = bc1[t];
    for (int k = 0; k < CLS_IN; ++k) acc += p[k] * Wc1[k * CLS_HID + t];
    hh[t] = lrelu(acc);
    __syncthreads();
    if (t < N_CLASSES) {
        float a2 = bc2[t];
        for (int k = 0; k < CLS_HID; ++k) a2 += hh[k] * Wc2[k * N_CLASSES + t];
        out[g * N_CLASSES + t] = a2;
    }
}

extern "C" void kernel_launch(void* const* d_in, const int* in_sizes, int n_in,
                              void* d_out, int out_size, void* d_ws, size_t ws_size,
                              hipStream_t stream) {
    const int*   deg   = (const int*)d_in[0];
    const int*   edges = (const int*)d_in[1];
    const int*   srcv  = edges;
    const int*   dstv  = edges + N_EDGES;
    const int*   batch = (const int*)d_in[2];
    const float* epsv  = (const float*)d_in[3];
    const float* W1    = (const float*)d_in[4];
    const float* b1    = (const float*)d_in[5];
    const float* W2    = (const float*)d_in[6];
    const float* b2    = (const float*)d_in[7];
    const float* bn_g  = (const float*)d_in[8];
    const float* bn_b  = (const float*)d_in[9];
    const float* Wc1   = (const float*)d_in[10];
    const float* bc1   = (const float*)d_in[11];
    const float* Wc2   = (const float*)d_in[12];
    const float* bc2   = (const float*)d_in[13];

    char* ws = (char*)d_ws;
    const size_t BUFB = (size_t)N_NODES * DIM * 2;   // 25,600,000 B (bf16)
    size_t off = 0;
    ushort* buf0   = (ushort*)(ws + off); off += BUFB;
    ushort* buf1   = (ushort*)(ws + off); off += BUFB;
    ushort* W1t    = (ushort*)(ws + off); off += 4 * DIM * DIM * 2;
    ushort* W2t    = (ushort*)(ws + off); off += 4 * DIM * DIM * 2;
    float*  pooled = (float*)(ws + off);  off += N_GRAPHS * CLS_IN * 4;
    float*  statsA = (float*)(ws + off);  off += 4 * 2 * DIM * 4;
    uint*   cursor = (uint*)(ws + off);   off += (NBUCK + 8) * 4;
    uint*   base   = (uint*)(ws + off);   off += (NBUCK + 8) * 4;
    int*    indptr = (int*)(ws + off);    off += (N_NODES + 8) * 4;
    int*    csr    = (int*)(ws + off);    off += (size_t)N_EDGES * 4;
    uint*   ebuf   = (uint*)(ws + off);   off += (size_t)NBUCK * BUCK_CAP * 4;  // 12.8 MB

    hipMemsetAsync(pooled, 0, N_GRAPHS * CLS_IN * 4, stream);
    hipMemsetAsync(statsA, 0, 4 * 2 * DIM * 4, stream);
    hipMemsetAsync(cursor, 0, NBUCK * 4, stream);

    k_convert_w<<<(8 * DIM * DIM + 255) / 256, 256, 0, stream>>>(W1, W2, W1t, W2t);
    k_build_x<<<(N_NODES * 64 + 255) / 256, 256, 0, stream>>>(deg, batch, (uint*)buf0, pooled);
    k_partition<<<(N_EDGES + 16383) / 16384, 1024, 0, stream>>>(srcv, dstv, cursor, ebuf);
    k_bases<<<1, 1024, 0, stream>>>(cursor, base, indptr);
    k_sort<<<NBUCK, 512, 0, stream>>>(ebuf, cursor, base, csr, indptr);

    const int layer_grid = (N_NODES + 63) / 64;   // 1563
    for (int l = 0; l < N_LAYERS; ++l) {
        float* stats = statsA + l * 2 * DIM;
        k_layer<<<layer_grid, 256, 0, stream>>>((const uint*)buf0, indptr, csr,
                                                W1t + l * DIM * DIM, b1 + l * DIM,
                                                W2t + l * DIM * DIM, b2 + l * DIM,
                                                buf1, stats, epsv, l);
        k_bnpool<<<(N_NODES + PROWS - 1) / PROWS, 256, 0, stream>>>(
            (const uint*)buf1, (uint*)buf0, stats, bn_g, bn_b, l, batch,
            pooled, DIM * (l + 1));
    }

    k_classifier<<<N_GRAPHS, 256, 0, stream>>>(pooled, Wc1, bc1, Wc2, bc2, (float*)d_out);
}

// Round 9
// 680.306 us; speedup vs baseline: 1.5169x; 1.5169x over previous
//
#include <hip/hip_runtime.h>
#include <hip/hip_bf16.h>

// GIN: N=100000, E=1.6M, G=64, D=128, L=4.
// R9: R7 structure (one-time CSR; separate gather / fused-MLP / bnpool kernels
// — R8 proved fusing gather+MFMA kills gather occupancy). Changes vs R7:
// gather uses 256-thread 64-node tiles (grid 1563, ~6.5KB LDS -> ~8 blocks/CU,
// better balance), memsets folded into k_convert_w, bnpool grid 2x wider.

#define N_NODES   100000
#define N_EDGES   1600000
#define N_GRAPHS  64
#define DIM       128
#define N_LAYERS  4
#define CLS_IN    640
#define CLS_HID   256
#define N_CLASSES 10
#define LRELU_SLOPE 0.01f
#define BN_EPS_F    1e-5f

#define NBUCK    782      // ceil(100000/128)  (CSR build granularity)
#define BUCK_CAP 4096
#define ECAP     1536     // per-64-node-tile LDS edge cap (avg 1024, +16 sd)

typedef __attribute__((ext_vector_type(8))) short bf16x8;
typedef __attribute__((ext_vector_type(4))) float f32x4;

__device__ __forceinline__ float lrelu(float x) { return x > 0.f ? x : LRELU_SLOPE * x; }

__device__ __forceinline__ ushort bf16r(float x) {
    uint a = __float_as_uint(x);
    return (ushort)((a + 0x7FFFu + ((a >> 16) & 1u)) >> 16);
}
__device__ __forceinline__ uint pack2(float x, float y) {
    uint a = __float_as_uint(x), b = __float_as_uint(y);
    a = (a + 0x7FFFu + ((a >> 16) & 1u)) >> 16;
    b = (b + 0x7FFFu + ((b >> 16) & 1u)) >> 16;
    return a | (b << 16);
}
__device__ __forceinline__ float2 unpack2(uint v) {
    return make_float2(__uint_as_float(v << 16), __uint_as_float(v & 0xFFFF0000u));
}

// ---------------- weight convert + workspace zero-init ----------------
__global__ void k_convert_w(const float* __restrict__ W1, const float* __restrict__ W2,
                            ushort* __restrict__ W1t, ushort* __restrict__ W2t,
                            uint* __restrict__ cursor, float* __restrict__ statsA,
                            float* __restrict__ pooled) {
    int gid = blockIdx.x * blockDim.x + threadIdx.x;   // 8 * 16384
    if (blockIdx.x == 0) {   // zero scratch (stream order covers later kernels)
        for (int i = threadIdx.x; i < NBUCK; i += 256) cursor[i] = 0u;
        for (int i = threadIdx.x; i < 4 * 2 * DIM; i += 256) statsA[i] = 0.f;
    }
    // pooled zeroed by many blocks (40960 floats)
    for (int i = gid; i < N_GRAPHS * CLS_IN; i += 512 * 256) pooled[i] = 0.f;
    if (gid >= 8 * DIM * DIM) return;
    int mat = gid >> 14, idx = gid & 16383;
    int k = idx >> 7, n = idx & 127;
    const float* src = (mat < 4) ? (W1 + mat * DIM * DIM) : (W2 + (mat - 4) * DIM * DIM);
    ushort* dst = (mat < 4) ? (W1t + mat * DIM * DIM) : (W2t + (mat - 4) * DIM * DIM);
    dst[n * DIM + k] = bf16r(src[k * DIM + n]);
}

// ---------------- initial one-hot features (bf16, row-major) + zs[0] pooling ----------------
__global__ void k_build_x(const int* __restrict__ deg, const int* __restrict__ batch,
                          uint* __restrict__ x, float* __restrict__ pooled) {
    int gid = blockIdx.x * blockDim.x + threadIdx.x;   // one per uint (2 bf16)
    if (gid >= N_NODES * 64) return;
    int i = gid >> 6, c = gid & 63;
    int d = deg[i];
    uint v = 0;
    if ((d >> 1) == c) v = 0x3F80u << (16 * (d & 1));
    x[gid] = v;
    if (c == 0) atomicAdd(&pooled[batch[i] * CLS_IN + d], 1.0f);
}

// ---------------- bucketed edge partition ----------------
// bucket b = dst >> 7; packed = (dst&127)<<17 | src
__global__ void __launch_bounds__(1024) k_partition(const int* __restrict__ src,
                                                    const int* __restrict__ dst,
                                                    uint* __restrict__ cursor,
                                                    uint* __restrict__ ebuf) {
    __shared__ uint hist[NBUCK];
    __shared__ uint basev[NBUCK];
    int t = threadIdx.x;
    for (int b = t; b < NBUCK; b += 1024) hist[b] = 0;
    __syncthreads();
    int e0 = blockIdx.x * 16384;
    uint msrc[16], mdst[16], mrank[16];
#pragma unroll
    for (int i = 0; i < 16; ++i) {
        int e = e0 + i * 1024 + t;
        if (e < N_EDGES) {
            msrc[i] = (uint)src[e];
            mdst[i] = (uint)dst[e];
            mrank[i] = atomicAdd(&hist[mdst[i] >> 7], 1u);
        } else mdst[i] = 0xFFFFFFFFu;
    }
    __syncthreads();
    for (int b = t; b < NBUCK; b += 1024) {
        uint c = hist[b];
        basev[b] = c ? (uint)(b * BUCK_CAP) + atomicAdd(&cursor[b], c) : 0u;
    }
    __syncthreads();
#pragma unroll
    for (int i = 0; i < 16; ++i) {
        if (mdst[i] != 0xFFFFFFFFu) {
            uint b = mdst[i] >> 7;
            ebuf[basev[b] + mrank[i]] = ((mdst[i] & 127u) << 17) | msrc[i];
        }
    }
}

// ---------------- bucket base offsets (exclusive scan of counts) ----------------
__global__ void __launch_bounds__(1024) k_bases(const uint* __restrict__ cursor,
                                                uint* __restrict__ base,
                                                int* __restrict__ indptr) {
    __shared__ uint sh[1024];
    int t = threadIdx.x;
    uint v = (t < NBUCK) ? min(cursor[t], (uint)BUCK_CAP) : 0u;
    sh[t] = v; __syncthreads();
    for (int off = 1; off < 1024; off <<= 1) {
        uint add = (t >= off) ? sh[t - off] : 0u;
        __syncthreads();
        sh[t] += add;
        __syncthreads();
    }
    if (t < NBUCK) base[t] = sh[t] - v;          // exclusive
    if (t == NBUCK - 1) indptr[N_NODES] = (int)sh[t];
}

// ---------------- per-bucket LDS counting sort -> compacted CSR + indptr ----------------
__global__ void __launch_bounds__(512) k_sort(const uint* __restrict__ ebuf,
                                              const uint* __restrict__ cursor,
                                              const uint* __restrict__ base,
                                              int* __restrict__ csr,
                                              int* __restrict__ indptr) {
    __shared__ uint sortedL[BUCK_CAP];
    __shared__ uint hist[128];
    __shared__ uint startv[129];
    const int t = threadIdx.x, b = blockIdx.x;
    int cnt = (int)cursor[b]; if (cnt > BUCK_CAP) cnt = BUCK_CAP;
    if (t < 128) hist[t] = 0;
    __syncthreads();
    uint ent[8], rank[8];
    const uint* ep = ebuf + b * BUCK_CAP;
#pragma unroll
    for (int k = 0; k < 8; ++k) {
        int i = t + k * 512;
        if (i < cnt) { ent[k] = ep[i]; rank[k] = atomicAdd(&hist[ent[k] >> 17], 1u); }
    }
    __syncthreads();
    if (t < 128) startv[t + 1] = hist[t];
    if (t == 0) startv[0] = 0;
    __syncthreads();
    for (int off = 1; off < 128; off <<= 1) {
        uint add = (t < 128 && t >= off) ? startv[t + 1 - off] : 0u;
        __syncthreads();
        if (t < 128 && t >= off) startv[t + 1] += add;
        __syncthreads();
    }
#pragma unroll
    for (int k = 0; k < 8; ++k) {
        int i = t + k * 512;
        if (i < cnt) sortedL[startv[ent[k] >> 17] + rank[k]] = ent[k];
    }
    __syncthreads();
    int gbase = (int)base[b];
    for (int i = t; i < cnt; i += 512)
        csr[gbase + i] = (int)(sortedL[i] & 0x1FFFFu);
    if (t < 128) {
        int node = b * 128 + t;
        if (node < N_NODES) indptr[node] = gbase + (int)startv[t];
    }
}

// ---------------- gather: 64-node tile, LDS-staged edges, register accumulate ----------------
// out[n] = (1+eps)*h[n] + sum_{src} h[src]; 4 waves x 16 nodes each.
__global__ void __launch_bounds__(256) k_agg5(const uint* __restrict__ h,
                                              const int* __restrict__ indptr,
                                              const int* __restrict__ csr,
                                              uint* __restrict__ out,
                                              const float* __restrict__ epsv, int layer) {
    __shared__ int eL[ECAP];    // 6 KB
    __shared__ int sv[65];
    const int t = threadIdx.x, lane = t & 63, wave = t >> 6;
    const int node0 = blockIdx.x * 64;
    if (t < 65) {
        int n = node0 + t;
        sv[t] = indptr[n > N_NODES ? N_NODES : n];
    }
    __syncthreads();
    const int gbase = sv[0];
    const int cnt = sv[64] - gbase;
    {
        int stg = cnt > ECAP ? ECAP : cnt;
        for (int i = t; i < stg; i += 256) eL[i] = csr[gbase + i];
    }
    __syncthreads();
    const float s = 1.0f + epsv[layer];
    for (int ri = 0; ri < 16; ++ri) {
        int r = wave * 16 + ri;
        int g = node0 + r;
        if (g >= N_NODES) break;
        int beg = sv[r] - gbase, end = sv[r + 1] - gbase;
        float2 own = unpack2(h[g * 64 + lane]);
        float ax = s * own.x, ay = s * own.y;
        if (end <= ECAP) {
            int j = beg;
            for (; j + 4 <= end; j += 4) {
                int i0 = eL[j], i1 = eL[j + 1], i2 = eL[j + 2], i3 = eL[j + 3];
                uint w0 = h[i0 * 64 + lane], w1 = h[i1 * 64 + lane];
                uint w2 = h[i2 * 64 + lane], w3 = h[i3 * 64 + lane];
                float2 f0 = unpack2(w0), f1 = unpack2(w1), f2 = unpack2(w2), f3 = unpack2(w3);
                ax += (f0.x + f1.x) + (f2.x + f3.x);
                ay += (f0.y + f1.y) + (f2.y + f3.y);
            }
            for (; j < end; ++j) {
                float2 f = unpack2(h[eL[j] * 64 + lane]);
                ax += f.x; ay += f.y;
            }
        } else {   // overflow fallback (statistically never)
            for (int j = beg; j < end; ++j) {
                int u = csr[gbase + j];
                float2 f = unpack2(h[u * 64 + lane]);
                ax += f.x; ay += f.y;
            }
        }
        out[g * 64 + lane] = pack2(ax, ay);
    }
}

// ---------------- fused MLP: C = (lrelu(A@W1t^T + b1))@W2t^T + b2, + BN stats ----------------
#define MLP_LDS_BYTES 69632
__global__ void __launch_bounds__(256) k_mlp(const ushort* __restrict__ A,
                                             const ushort* __restrict__ W1t,
                                             const float* __restrict__ b1,
                                             const ushort* __restrict__ W2t,
                                             const float* __restrict__ b2,
                                             ushort* __restrict__ C,
                                             float* __restrict__ stats) {
    __shared__ char pool[MLP_LDS_BYTES];
    ushort* As = (ushort*)pool;             // [128][136] bf16: A, then H1
    ushort* Ws = (ushort*)(pool + 34816);   // [128][136] bf16: W1t, then W2t
    float*  Cs = (float*)pool;              // [128][132] fp32 (aliases after phase-2)
    const int t = threadIdx.x;
    const int row0 = blockIdx.x * 128;
    {   // stage A tile + W1 tile
        int r = t >> 1, hh = t & 1;
        uint4* l = (uint4*)(As + r * 136 + hh * 64);
        if (row0 + r < N_NODES) {
            const uint4* g = (const uint4*)(A + (size_t)(row0 + r) * DIM + hh * 64);
#pragma unroll
            for (int k = 0; k < 8; ++k) l[k] = g[k];
        } else {
            uint4 z = make_uint4(0, 0, 0, 0);
#pragma unroll
            for (int k = 0; k < 8; ++k) l[k] = z;
        }
        const uint4* gw = (const uint4*)(W1t + r * DIM + hh * 64);
        uint4* lw = (uint4*)(Ws + r * 136 + hh * 64);
#pragma unroll
        for (int k = 0; k < 8; ++k) lw[k] = gw[k];
    }
    __syncthreads();
    const int lane = t & 63, wave = t >> 6;
    const int q = lane >> 4, m = lane & 15;
    const int R = (wave >> 1) * 64, Cb = (wave & 1) * 64;
    // ---- phase 1: H1 = A @ W1 ----
    {
        f32x4 acc[4][4] = {};
#pragma unroll
        for (int ks = 0; ks < 4; ++ks) {
            bf16x8 a[4], b[4];
#pragma unroll
            for (int i = 0; i < 4; ++i)
                a[i] = *(const bf16x8*)(As + (R + i * 16 + m) * 136 + ks * 32 + q * 8);
#pragma unroll
            for (int j = 0; j < 4; ++j)
                b[j] = *(const bf16x8*)(Ws + (Cb + j * 16 + m) * 136 + ks * 32 + q * 8);
#pragma unroll
            for (int i = 0; i < 4; ++i)
#pragma unroll
                for (int j = 0; j < 4; ++j)
                    acc[i][j] = __builtin_amdgcn_mfma_f32_16x16x32_bf16(a[i], b[j], acc[i][j], 0, 0, 0);
        }
        __syncthreads();   // all phase-1 LDS reads done
        float bias1[4];
#pragma unroll
        for (int j = 0; j < 4; ++j) bias1[j] = b1[Cb + j * 16 + m];
#pragma unroll
        for (int i = 0; i < 4; ++i)
#pragma unroll
            for (int j = 0; j < 4; ++j)
#pragma unroll
                for (int r = 0; r < 4; ++r)
                    As[(R + i * 16 + q * 4 + r) * 136 + Cb + j * 16 + m] =
                        bf16r(lrelu(acc[i][j][r] + bias1[j]));
        {
            int r = t >> 1, hh = t & 1;
            const uint4* gw = (const uint4*)(W2t + r * DIM + hh * 64);
            uint4* lw = (uint4*)(Ws + r * 136 + hh * 64);
#pragma unroll
            for (int k = 0; k < 8; ++k) lw[k] = gw[k];
        }
    }
    __syncthreads();
    // ---- phase 2: C = H1 @ W2 ----
    f32x4 acc2[4][4] = {};
#pragma unroll
    for (int ks = 0; ks < 4; ++ks) {
        bf16x8 a[4], b[4];
#pragma unroll
        for (int i = 0; i < 4; ++i)
            a[i] = *(const bf16x8*)(As + (R + i * 16 + m) * 136 + ks * 32 + q * 8);
#pragma unroll
        for (int j = 0; j < 4; ++j)
            b[j] = *(const bf16x8*)(Ws + (Cb + j * 16 + m) * 136 + ks * 32 + q * 8);
#pragma unroll
        for (int i = 0; i < 4; ++i)
#pragma unroll
            for (int j = 0; j < 4; ++j)
                acc2[i][j] = __builtin_amdgcn_mfma_f32_16x16x32_bf16(a[i], b[j], acc2[i][j], 0, 0, 0);
    }
    __syncthreads();   // all phase-2 LDS reads done; safe to alias Cs
    float bias2[4];
#pragma unroll
    for (int j = 0; j < 4; ++j) bias2[j] = b2[Cb + j * 16 + m];
#pragma unroll
    for (int i = 0; i < 4; ++i)
#pragma unroll
        for (int j = 0; j < 4; ++j)
#pragma unroll
            for (int r = 0; r < 4; ++r)
                Cs[(R + i * 16 + q * 4 + r) * 132 + Cb + j * 16 + m] = acc2[i][j][r] + bias2[j];
    __syncthreads();
    if (t < DIM) {   // BN stats (pre-activation sums)
        int rows = N_NODES - row0; if (rows > 128) rows = 128;
        float s1 = 0.f, s2 = 0.f;
        for (int r = 0; r < rows; ++r) { float v = Cs[r * 132 + t]; s1 += v; s2 += v * v; }
        atomicAdd(&stats[t], s1);
        atomicAdd(&stats[DIM + t], s2);
    }
    {   // bf16 pack + store
        int r = t >> 1, hh = t & 1;
        if (row0 + r < N_NODES) {
            uint4* outp = (uint4*)(C + (size_t)(row0 + r) * DIM + hh * 64);
#pragma unroll
            for (int k = 0; k < 8; ++k) {
                float4 v0 = *(const float4*)(Cs + r * 132 + hh * 64 + k * 8);
                float4 v1 = *(const float4*)(Cs + r * 132 + hh * 64 + k * 8 + 4);
                uint4 o;
                o.x = pack2(v0.x, v0.y); o.y = pack2(v0.z, v0.w);
                o.z = pack2(v1.x, v1.y); o.w = pack2(v1.z, v1.w);
                outp[k] = o;
            }
        }
    }
}

// ---------------- BN apply (inline finalize) + lrelu + fused pooling ----------------
#define PROWS 64
__global__ void __launch_bounds__(256) k_bnpool(const uint* __restrict__ src,
                                                uint* __restrict__ dst,
                                                const float* __restrict__ stats,
                                                const float* __restrict__ bn_g,
                                                const float* __restrict__ bn_b, int layer,
                                                const int* __restrict__ batch,
                                                float* __restrict__ pooled, int colOff) {
    int c = threadIdx.x & 63;
    int chunk = threadIdx.x >> 6;
    int r0 = blockIdx.x * PROWS + chunk * (PROWS / 4);
    float sc0, sh0, sc1, sh1;
    {
        int f0 = 2 * c, f1 = 2 * c + 1;
        float m0 = stats[f0] * (1.0f / N_NODES);
        float m1 = stats[f1] * (1.0f / N_NODES);
        float v0 = stats[DIM + f0] * (1.0f / N_NODES) - m0 * m0;
        float v1 = stats[DIM + f1] * (1.0f / N_NODES) - m1 * m1;
        sc0 = bn_g[layer * DIM + f0] * rsqrtf(v0 + BN_EPS_F);
        sc1 = bn_g[layer * DIM + f1] * rsqrtf(v1 + BN_EPS_F);
        sh0 = bn_b[layer * DIM + f0] - m0 * sc0;
        sh1 = bn_b[layer * DIM + f1] - m1 * sc1;
    }
    int curg = -1;
    float a0 = 0.f, a1 = 0.f;
    for (int i = 0; i < PROWS / 4; ++i) {
        int r = r0 + i;
        if (r >= N_NODES) break;
        float2 v = unpack2(src[r * 64 + c]);
        float x0 = lrelu(v.x * sc0 + sh0);
        float x1 = lrelu(v.y * sc1 + sh1);
        dst[r * 64 + c] = pack2(x0, x1);
        int g = batch[r];
        if (g != curg) {
            if (curg >= 0) {
                atomicAdd(&pooled[curg * CLS_IN + colOff + 2 * c], a0);
                atomicAdd(&pooled[curg * CLS_IN + colOff + 2 * c + 1], a1);
            }
            curg = g; a0 = 0.f; a1 = 0.f;
        }
        a0 += x0; a1 += x1;
    }
    if (curg >= 0) {
        atomicAdd(&pooled[curg * CLS_IN + colOff + 2 * c], a0);
        atomicAdd(&pooled[curg * CLS_IN + colOff + 2 * c + 1], a1);
    }
}

// ---------------- classifier head (fp32): one block per graph ----------------
__global__ void __launch_bounds__(256) k_classifier(const float* __restrict__ pooled,
                                                    const float* __restrict__ Wc1,
                                                    const float* __restrict__ bc1,
                                                    const float* __restrict__ Wc2,
                                                    const float* __restrict__ bc2,
                                                    float* __restrict__ out) {
    __shared__ float p[CLS_IN];
    __shared__ float hh[CLS_HID];
    int g = blockIdx.x, t = threadIdx.x;
    for (int j = t; j < CLS_IN; j += 256) p[j] = lrelu(pooled[g * CLS_IN + j]);
    __syncthreads();
    float acc = bc1[t];
    for (int k = 0; k < CLS_IN; ++k) acc += p[k] * Wc1[k * CLS_HID + t];
    hh[t] = lrelu(acc);
    __syncthreads();
    if (t < N_CLASSES) {
        float a2 = bc2[t];
        for (int k = 0; k < CLS_HID; ++k) a2 += hh[k] * Wc2[k * N_CLASSES + t];
        out[g * N_CLASSES + t] = a2;
    }
}

extern "C" void kernel_launch(void* const* d_in, const int* in_sizes, int n_in,
                              void* d_out, int out_size, void* d_ws, size_t ws_size,
                              hipStream_t stream) {
    const int*   deg   = (const int*)d_in[0];
    const int*   edges = (const int*)d_in[1];
    const int*   srcv  = edges;
    const int*   dstv  = edges + N_EDGES;
    const int*   batch = (const int*)d_in[2];
    const float* epsv  = (const float*)d_in[3];
    const float* W1    = (const float*)d_in[4];
    const float* b1    = (const float*)d_in[5];
    const float* W2    = (const float*)d_in[6];
    const float* b2    = (const float*)d_in[7];
    const float* bn_g  = (const float*)d_in[8];
    const float* bn_b  = (const float*)d_in[9];
    const float* Wc1   = (const float*)d_in[10];
    const float* bc1   = (const float*)d_in[11];
    const float* Wc2   = (const float*)d_in[12];
    const float* bc2   = (const float*)d_in[13];

    char* ws = (char*)d_ws;
    const size_t BUFB = (size_t)N_NODES * DIM * 2;   // 25,600,000 B (bf16)
    size_t off = 0;
    ushort* buf0   = (ushort*)(ws + off); off += BUFB;
    ushort* buf1   = (ushort*)(ws + off); off += BUFB;
    ushort* W1t    = (ushort*)(ws + off); off += 4 * DIM * DIM * 2;
    ushort* W2t    = (ushort*)(ws + off); off += 4 * DIM * DIM * 2;
    float*  pooled = (float*)(ws + off);  off += N_GRAPHS * CLS_IN * 4;
    float*  statsA = (float*)(ws + off);  off += 4 * 2 * DIM * 4;
    uint*   cursor = (uint*)(ws + off);   off += (NBUCK + 8) * 4;
    uint*   base   = (uint*)(ws + off);   off += (NBUCK + 8) * 4;
    int*    indptr = (int*)(ws + off);    off += (N_NODES + 8) * 4;
    int*    csr    = (int*)(ws + off);    off += (size_t)N_EDGES * 4;
    uint*   ebuf   = (uint*)(ws + off);   off += (size_t)NBUCK * BUCK_CAP * 4;  // 12.8 MB

    // init (cursor/stats/pooled zeroing) folded into k_convert_w; stream order
    // guarantees completion before k_build_x / k_partition / k_mlp use them.
    k_convert_w<<<512, 256, 0, stream>>>(W1, W2, W1t, W2t, cursor, statsA, pooled);
    k_build_x<<<(N_NODES * 64 + 255) / 256, 256, 0, stream>>>(deg, batch, (uint*)buf0, pooled);
    k_partition<<<(N_EDGES + 16383) / 16384, 1024, 0, stream>>>(srcv, dstv, cursor, ebuf);
    k_bases<<<1, 1024, 0, stream>>>(cursor, base, indptr);
    k_sort<<<NBUCK, 512, 0, stream>>>(ebuf, cursor, base, csr, indptr);

    const int gemm_grid = (N_NODES + 127) / 128;   // 782
    const int agg_grid  = (N_NODES + 63) / 64;     // 1563
    for (int l = 0; l < N_LAYERS; ++l) {
        float* stats = statsA + l * 2 * DIM;
        k_agg5<<<agg_grid, 256, 0, stream>>>((const uint*)buf0, indptr, csr,
                                             (uint*)buf1, epsv, l);
        k_mlp<<<gemm_grid, 256, 0, stream>>>(buf1, W1t + l * DIM * DIM, b1 + l * DIM,
                                             W2t + l * DIM * DIM, b2 + l * DIM,
                                             buf1, stats);
        k_bnpool<<<(N_NODES + PROWS - 1) / PROWS, 256, 0, stream>>>(
            (const uint*)buf1, (uint*)buf0, stats, bn_g, bn_b, l, batch,
            pooled, DIM * (l + 1));
    }

    k_classifier<<<N_GRAPHS, 256, 0, stream>>>(pooled, Wc1, bc1, Wc2, bc2, (float*)d_out);
}

// Round 10
// 670.273 us; speedup vs baseline: 1.5396x; 1.0150x over previous
//
#include <hip/hip_runtime.h>
#include <hip/hip_bf16.h>

// GIN: N=100000, E=1.6M, G=64, D=128, L=4.
// R10: gather reworked for memory-level parallelism: wave processes EDGE PAIRS
// (half-wave per edge row, uint2/lane = 512B per load instr, 8-edge unroll =
// 2KB in flight/wave, shfl_xor(32) merge), 128-thread blocks / 32-node tiles.
// Rest identical to R9: one-time CSR, fused dual-GEMM k_mlp, fused bnpool.

#define N_NODES   100000
#define N_EDGES   1600000
#define N_GRAPHS  64
#define DIM       128
#define N_LAYERS  4
#define CLS_IN    640
#define CLS_HID   256
#define N_CLASSES 10
#define LRELU_SLOPE 0.01f
#define BN_EPS_F    1e-5f

#define NBUCK    782      // ceil(100000/128)  (CSR build granularity)
#define BUCK_CAP 4096
#define ECAP2    1024     // per-32-node-tile LDS edge cap (avg 512)

typedef __attribute__((ext_vector_type(8))) short bf16x8;
typedef __attribute__((ext_vector_type(4))) float f32x4;

__device__ __forceinline__ float lrelu(float x) { return x > 0.f ? x : LRELU_SLOPE * x; }

__device__ __forceinline__ ushort bf16r(float x) {
    uint a = __float_as_uint(x);
    return (ushort)((a + 0x7FFFu + ((a >> 16) & 1u)) >> 16);
}
__device__ __forceinline__ uint pack2(float x, float y) {
    uint a = __float_as_uint(x), b = __float_as_uint(y);
    a = (a + 0x7FFFu + ((a >> 16) & 1u)) >> 16;
    b = (b + 0x7FFFu + ((b >> 16) & 1u)) >> 16;
    return a | (b << 16);
}
__device__ __forceinline__ float2 unpack2(uint v) {
    return make_float2(__uint_as_float(v << 16), __uint_as_float(v & 0xFFFF0000u));
}

// ---------------- weight convert + workspace zero-init ----------------
__global__ void k_convert_w(const float* __restrict__ W1, const float* __restrict__ W2,
                            ushort* __restrict__ W1t, ushort* __restrict__ W2t,
                            uint* __restrict__ cursor, float* __restrict__ statsA,
                            float* __restrict__ pooled) {
    int gid = blockIdx.x * blockDim.x + threadIdx.x;   // 8 * 16384
    if (blockIdx.x == 0) {
        for (int i = threadIdx.x; i < NBUCK; i += 256) cursor[i] = 0u;
        for (int i = threadIdx.x; i < 4 * 2 * DIM; i += 256) statsA[i] = 0.f;
    }
    for (int i = gid; i < N_GRAPHS * CLS_IN; i += 512 * 256) pooled[i] = 0.f;
    if (gid >= 8 * DIM * DIM) return;
    int mat = gid >> 14, idx = gid & 16383;
    int k = idx >> 7, n = idx & 127;
    const float* src = (mat < 4) ? (W1 + mat * DIM * DIM) : (W2 + (mat - 4) * DIM * DIM);
    ushort* dst = (mat < 4) ? (W1t + mat * DIM * DIM) : (W2t + (mat - 4) * DIM * DIM);
    dst[n * DIM + k] = bf16r(src[k * DIM + n]);
}

// ---------------- initial one-hot features (bf16, row-major) + zs[0] pooling ----------------
__global__ void k_build_x(const int* __restrict__ deg, const int* __restrict__ batch,
                          uint* __restrict__ x, float* __restrict__ pooled) {
    int gid = blockIdx.x * blockDim.x + threadIdx.x;   // one per uint (2 bf16)
    if (gid >= N_NODES * 64) return;
    int i = gid >> 6, c = gid & 63;
    int d = deg[i];
    uint v = 0;
    if ((d >> 1) == c) v = 0x3F80u << (16 * (d & 1));
    x[gid] = v;
    if (c == 0) atomicAdd(&pooled[batch[i] * CLS_IN + d], 1.0f);
}

// ---------------- bucketed edge partition ----------------
__global__ void __launch_bounds__(1024) k_partition(const int* __restrict__ src,
                                                    const int* __restrict__ dst,
                                                    uint* __restrict__ cursor,
                                                    uint* __restrict__ ebuf) {
    __shared__ uint hist[NBUCK];
    __shared__ uint basev[NBUCK];
    int t = threadIdx.x;
    for (int b = t; b < NBUCK; b += 1024) hist[b] = 0;
    __syncthreads();
    int e0 = blockIdx.x * 16384;
    uint msrc[16], mdst[16], mrank[16];
#pragma unroll
    for (int i = 0; i < 16; ++i) {
        int e = e0 + i * 1024 + t;
        if (e < N_EDGES) {
            msrc[i] = (uint)src[e];
            mdst[i] = (uint)dst[e];
            mrank[i] = atomicAdd(&hist[mdst[i] >> 7], 1u);
        } else mdst[i] = 0xFFFFFFFFu;
    }
    __syncthreads();
    for (int b = t; b < NBUCK; b += 1024) {
        uint c = hist[b];
        basev[b] = c ? (uint)(b * BUCK_CAP) + atomicAdd(&cursor[b], c) : 0u;
    }
    __syncthreads();
#pragma unroll
    for (int i = 0; i < 16; ++i) {
        if (mdst[i] != 0xFFFFFFFFu) {
            uint b = mdst[i] >> 7;
            ebuf[basev[b] + mrank[i]] = ((mdst[i] & 127u) << 17) | msrc[i];
        }
    }
}

// ---------------- bucket base offsets (exclusive scan of counts) ----------------
__global__ void __launch_bounds__(1024) k_bases(const uint* __restrict__ cursor,
                                                uint* __restrict__ base,
                                                int* __restrict__ indptr) {
    __shared__ uint sh[1024];
    int t = threadIdx.x;
    uint v = (t < NBUCK) ? min(cursor[t], (uint)BUCK_CAP) : 0u;
    sh[t] = v; __syncthreads();
    for (int off = 1; off < 1024; off <<= 1) {
        uint add = (t >= off) ? sh[t - off] : 0u;
        __syncthreads();
        sh[t] += add;
        __syncthreads();
    }
    if (t < NBUCK) base[t] = sh[t] - v;          // exclusive
    if (t == NBUCK - 1) indptr[N_NODES] = (int)sh[t];
}

// ---------------- per-bucket LDS counting sort -> compacted CSR + indptr ----------------
__global__ void __launch_bounds__(512) k_sort(const uint* __restrict__ ebuf,
                                              const uint* __restrict__ cursor,
                                              const uint* __restrict__ base,
                                              int* __restrict__ csr,
                                              int* __restrict__ indptr) {
    __shared__ uint sortedL[BUCK_CAP];
    __shared__ uint hist[128];
    __shared__ uint startv[129];
    const int t = threadIdx.x, b = blockIdx.x;
    int cnt = (int)cursor[b]; if (cnt > BUCK_CAP) cnt = BUCK_CAP;
    if (t < 128) hist[t] = 0;
    __syncthreads();
    uint ent[8], rank[8];
    const uint* ep = ebuf + b * BUCK_CAP;
#pragma unroll
    for (int k = 0; k < 8; ++k) {
        int i = t + k * 512;
        if (i < cnt) { ent[k] = ep[i]; rank[k] = atomicAdd(&hist[ent[k] >> 17], 1u); }
    }
    __syncthreads();
    if (t < 128) startv[t + 1] = hist[t];
    if (t == 0) startv[0] = 0;
    __syncthreads();
    for (int off = 1; off < 128; off <<= 1) {
        uint add = (t < 128 && t >= off) ? startv[t + 1 - off] : 0u;
        __syncthreads();
        if (t < 128 && t >= off) startv[t + 1] += add;
        __syncthreads();
    }
#pragma unroll
    for (int k = 0; k < 8; ++k) {
        int i = t + k * 512;
        if (i < cnt) sortedL[startv[ent[k] >> 17] + rank[k]] = ent[k];
    }
    __syncthreads();
    int gbase = (int)base[b];
    for (int i = t; i < cnt; i += 512)
        csr[gbase + i] = (int)(sortedL[i] & 0x1FFFFu);
    if (t < 128) {
        int node = b * 128 + t;
        if (node < N_NODES) indptr[node] = gbase + (int)startv[t];
    }
}

// ---------------- gather: edge-pair half-wave uint2 loads, register accumulate ----------------
// out[n] = (1+eps)*h[n] + sum_{src} h[src]; block = 128 thr = 2 waves = 32 nodes.
__global__ void __launch_bounds__(128) k_agg6(const uint* __restrict__ h,
                                              const int* __restrict__ indptr,
                                              const int* __restrict__ csr,
                                              uint* __restrict__ out,
                                              const float* __restrict__ epsv, int layer) {
    __shared__ int eL[ECAP2];   // 4 KB
    __shared__ int sv[33];
    const int t = threadIdx.x, lane = t & 63, wave = t >> 6;
    const int half = lane >> 5, c = lane & 31;   // uint2 column (4 bf16 cols)
    const int node0 = blockIdx.x * 32;
    if (t < 33) {
        int n = node0 + t;
        sv[t] = indptr[n > N_NODES ? N_NODES : n];
    }
    __syncthreads();
    const int gbase = sv[0];
    const int cnt = sv[32] - gbase;
    const bool inLds = (cnt <= ECAP2);
    {
        int stg = inLds ? cnt : 0;
        for (int i = t; i < stg; i += 128) eL[i] = csr[gbase + i];
    }
    __syncthreads();
    const float s = 1.0f + epsv[layer];
    for (int ri = 0; ri < 16; ++ri) {
        int r = wave * 16 + ri;
        int g = node0 + r;
        if (g >= N_NODES) break;
        int beg = sv[r] - gbase, end = sv[r + 1] - gbase;
        // own row: half 0 only (half 1 contributes 0, merged by shfl_xor)
        float a0, a1, a2, a3;
        {
            uint2 own = half ? make_uint2(0u, 0u)
                             : ((const uint2*)(h + (size_t)g * 64))[c];
            float2 o0 = unpack2(own.x), o1 = unpack2(own.y);
            a0 = s * o0.x; a1 = s * o0.y; a2 = s * o1.x; a3 = s * o1.y;
        }
        int j = beg;
        if (inLds) {
            for (; j + 8 <= end; j += 8) {
                int i0 = eL[j + half],     i1 = eL[j + 2 + half];
                int i2 = eL[j + 4 + half], i3 = eL[j + 6 + half];
                uint2 w0 = ((const uint2*)(h + (size_t)i0 * 64))[c];
                uint2 w1 = ((const uint2*)(h + (size_t)i1 * 64))[c];
                uint2 w2 = ((const uint2*)(h + (size_t)i2 * 64))[c];
                uint2 w3 = ((const uint2*)(h + (size_t)i3 * 64))[c];
                float2 p;
                p = unpack2(w0.x); a0 += p.x; a1 += p.y;
                p = unpack2(w0.y); a2 += p.x; a3 += p.y;
                p = unpack2(w1.x); a0 += p.x; a1 += p.y;
                p = unpack2(w1.y); a2 += p.x; a3 += p.y;
                p = unpack2(w2.x); a0 += p.x; a1 += p.y;
                p = unpack2(w2.y); a2 += p.x; a3 += p.y;
                p = unpack2(w3.x); a0 += p.x; a1 += p.y;
                p = unpack2(w3.y); a2 += p.x; a3 += p.y;
            }
            for (; j < end; j += 2) {
                int jj = j + half;
                bool valid = jj < end;
                int iu = eL[valid ? jj : j];
                uint2 w = ((const uint2*)(h + (size_t)iu * 64))[c];
                if (valid) {
                    float2 p;
                    p = unpack2(w.x); a0 += p.x; a1 += p.y;
                    p = unpack2(w.y); a2 += p.x; a3 += p.y;
                }
            }
        } else {   // overflow fallback (statistically never)
            for (; j < end; j += 2) {
                int jj = j + half;
                bool valid = jj < end;
                int iu = csr[gbase + (valid ? jj : j)];
                uint2 w = ((const uint2*)(h + (size_t)iu * 64))[c];
                if (valid) {
                    float2 p;
                    p = unpack2(w.x); a0 += p.x; a1 += p.y;
                    p = unpack2(w.y); a2 += p.x; a3 += p.y;
                }
            }
        }
        // merge halves
        a0 += __shfl_xor(a0, 32);
        a1 += __shfl_xor(a1, 32);
        a2 += __shfl_xor(a2, 32);
        a3 += __shfl_xor(a3, 32);
        if (!half) {
            uint2 o;
            o.x = pack2(a0, a1);
            o.y = pack2(a2, a3);
            ((uint2*)(out + (size_t)g * 64))[c] = o;
        }
    }
}

// ---------------- fused MLP: C = (lrelu(A@W1t^T + b1))@W2t^T + b2, + BN stats ----------------
#define MLP_LDS_BYTES 69632
__global__ void __launch_bounds__(256) k_mlp(const ushort* __restrict__ A,
                                             const ushort* __restrict__ W1t,
                                             const float* __restrict__ b1,
                                             const ushort* __restrict__ W2t,
                                             const float* __restrict__ b2,
                                             ushort* __restrict__ C,
                                             float* __restrict__ stats) {
    __shared__ char pool[MLP_LDS_BYTES];
    ushort* As = (ushort*)pool;             // [128][136] bf16: A, then H1
    ushort* Ws = (ushort*)(pool + 34816);   // [128][136] bf16: W1t, then W2t
    float*  Cs = (float*)pool;              // [128][132] fp32 (aliases after phase-2)
    const int t = threadIdx.x;
    const int row0 = blockIdx.x * 128;
    {   // stage A tile + W1 tile
        int r = t >> 1, hh = t & 1;
        uint4* l = (uint4*)(As + r * 136 + hh * 64);
        if (row0 + r < N_NODES) {
            const uint4* g = (const uint4*)(A + (size_t)(row0 + r) * DIM + hh * 64);
#pragma unroll
            for (int k = 0; k < 8; ++k) l[k] = g[k];
        } else {
            uint4 z = make_uint4(0, 0, 0, 0);
#pragma unroll
            for (int k = 0; k < 8; ++k) l[k] = z;
        }
        const uint4* gw = (const uint4*)(W1t + r * DIM + hh * 64);
        uint4* lw = (uint4*)(Ws + r * 136 + hh * 64);
#pragma unroll
        for (int k = 0; k < 8; ++k) lw[k] = gw[k];
    }
    __syncthreads();
    const int lane = t & 63, wave = t >> 6;
    const int q = lane >> 4, m = lane & 15;
    const int R = (wave >> 1) * 64, Cb = (wave & 1) * 64;
    // ---- phase 1: H1 = A @ W1 ----
    {
        f32x4 acc[4][4] = {};
#pragma unroll
        for (int ks = 0; ks < 4; ++ks) {
            bf16x8 a[4], b[4];
#pragma unroll
            for (int i = 0; i < 4; ++i)
                a[i] = *(const bf16x8*)(As + (R + i * 16 + m) * 136 + ks * 32 + q * 8);
#pragma unroll
            for (int j = 0; j < 4; ++j)
                b[j] = *(const bf16x8*)(Ws + (Cb + j * 16 + m) * 136 + ks * 32 + q * 8);
#pragma unroll
            for (int i = 0; i < 4; ++i)
#pragma unroll
                for (int j = 0; j < 4; ++j)
                    acc[i][j] = __builtin_amdgcn_mfma_f32_16x16x32_bf16(a[i], b[j], acc[i][j], 0, 0, 0);
        }
        __syncthreads();   // all phase-1 LDS reads done
        float bias1[4];
#pragma unroll
        for (int j = 0; j < 4; ++j) bias1[j] = b1[Cb + j * 16 + m];
#pragma unroll
        for (int i = 0; i < 4; ++i)
#pragma unroll
            for (int j = 0; j < 4; ++j)
#pragma unroll
                for (int r = 0; r < 4; ++r)
                    As[(R + i * 16 + q * 4 + r) * 136 + Cb + j * 16 + m] =
                        bf16r(lrelu(acc[i][j][r] + bias1[j]));
        {
            int r = t >> 1, hh = t & 1;
            const uint4* gw = (const uint4*)(W2t + r * DIM + hh * 64);
            uint4* lw = (uint4*)(Ws + r * 136 + hh * 64);
#pragma unroll
            for (int k = 0; k < 8; ++k) lw[k] = gw[k];
        }
    }
    __syncthreads();
    // ---- phase 2: C = H1 @ W2 ----
    f32x4 acc2[4][4] = {};
#pragma unroll
    for (int ks = 0; ks < 4; ++ks) {
        bf16x8 a[4], b[4];
#pragma unroll
        for (int i = 0; i < 4; ++i)
            a[i] = *(const bf16x8*)(As + (R + i * 16 + m) * 136 + ks * 32 + q * 8);
#pragma unroll
        for (int j = 0; j < 4; ++j)
            b[j] = *(const bf16x8*)(Ws + (Cb + j * 16 + m) * 136 + ks * 32 + q * 8);
#pragma unroll
        for (int i = 0; i < 4; ++i)
#pragma unroll
            for (int j = 0; j < 4; ++j)
                acc2[i][j] = __builtin_amdgcn_mfma_f32_16x16x32_bf16(a[i], b[j], acc2[i][j], 0, 0, 0);
    }
    __syncthreads();   // all phase-2 LDS reads done; safe to alias Cs
    float bias2[4];
#pragma unroll
    for (int j = 0; j < 4; ++j) bias2[j] = b2[Cb + j * 16 + m];
#pragma unroll
    for (int i = 0; i < 4; ++i)
#pragma unroll
        for (int j = 0; j < 4; ++j)
#pragma unroll
            for (int r = 0; r < 4; ++r)
                Cs[(R + i * 16 + q * 4 + r) * 132 + Cb + j * 16 + m] = acc2[i][j][r] + bias2[j];
    __syncthreads();
    if (t < DIM) {   // BN stats (pre-activation sums)
        int rows = N_NODES - row0; if (rows > 128) rows = 128;
        float s1 = 0.f, s2 = 0.f;
        for (int r = 0; r < rows; ++r) { float v = Cs[r * 132 + t]; s1 += v; s2 += v * v; }
        atomicAdd(&stats[t], s1);
        atomicAdd(&stats[DIM + t], s2);
    }
    {   // bf16 pack + store
        int r = t >> 1, hh = t & 1;
        if (row0 + r < N_NODES) {
            uint4* outp = (uint4*)(C + (size_t)(row0 + r) * DIM + hh * 64);
#pragma unroll
            for (int k = 0; k < 8; ++k) {
                float4 v0 = *(const float4*)(Cs + r * 132 + hh * 64 + k * 8);
                float4 v1 = *(const float4*)(Cs + r * 132 + hh * 64 + k * 8 + 4);
                uint4 o;
                o.x = pack2(v0.x, v0.y); o.y = pack2(v0.z, v0.w);
                o.z = pack2(v1.x, v1.y); o.w = pack2(v1.z, v1.w);
                outp[k] = o;
            }
        }
    }
}

// ---------------- BN apply (inline finalize) + lrelu + fused pooling ----------------
#define PROWS 64
__global__ void __launch_bounds__(256) k_bnpool(const uint* __restrict__ src,
                                                uint* __restrict__ dst,
                                                const float* __restrict__ stats,
                                                const float* __restrict__ bn_g,
                                                const float* __restrict__ bn_b, int layer,
                                                const int* __restrict__ batch,
                                                float* __restrict__ pooled, int colOff) {
    int c = threadIdx.x & 63;
    int chunk = threadIdx.x >> 6;
    int r0 = blockIdx.x * PROWS + chunk * (PROWS / 4);
    float sc0, sh0, sc1, sh1;
    {
        int f0 = 2 * c, f1 = 2 * c + 1;
        float m0 = stats[f0] * (1.0f / N_NODES);
        float m1 = stats[f1] * (1.0f / N_NODES);
        float v0 = stats[DIM + f0] * (1.0f / N_NODES) - m0 * m0;
        float v1 = stats[DIM + f1] * (1.0f / N_NODES) - m1 * m1;
        sc0 = bn_g[layer * DIM + f0] * rsqrtf(v0 + BN_EPS_F);
        sc1 = bn_g[layer * DIM + f1] * rsqrtf(v1 + BN_EPS_F);
        sh0 = bn_b[layer * DIM + f0] - m0 * sc0;
        sh1 = bn_b[layer * DIM + f1] - m1 * sc1;
    }
    int curg = -1;
    float a0 = 0.f, a1 = 0.f;
    for (int i = 0; i < PROWS / 4; ++i) {
        int r = r0 + i;
        if (r >= N_NODES) break;
        float2 v = unpack2(src[r * 64 + c]);
        float x0 = lrelu(v.x * sc0 + sh0);
        float x1 = lrelu(v.y * sc1 + sh1);
        dst[r * 64 + c] = pack2(x0, x1);
        int g = batch[r];
        if (g != curg) {
            if (curg >= 0) {
                atomicAdd(&pooled[curg * CLS_IN + colOff + 2 * c], a0);
                atomicAdd(&pooled[curg * CLS_IN + colOff + 2 * c + 1], a1);
            }
            curg = g; a0 = 0.f; a1 = 0.f;
        }
        a0 += x0; a1 += x1;
    }
    if (curg >= 0) {
        atomicAdd(&pooled[curg * CLS_IN + colOff + 2 * c], a0);
        atomicAdd(&pooled[curg * CLS_IN + colOff + 2 * c + 1], a1);
    }
}

// ---------------- classifier head (fp32): one block per graph ----------------
__global__ void __launch_bounds__(256) k_classifier(const float* __restrict__ pooled,
                                                    const float* __restrict__ Wc1,
                                                    const float* __restrict__ bc1,
                                                    const float* __restrict__ Wc2,
                                                    const float* __restrict__ bc2,
                                                    float* __restrict__ out) {
    __shared__ float p[CLS_IN];
    __shared__ float hh[CLS_HID];
    int g = blockIdx.x, t = threadIdx.x;
    for (int j = t; j < CLS_IN; j += 256) p[j] = lrelu(pooled[g * CLS_IN + j]);
    __syncthreads();
    float acc = bc1[t];
    for (int k = 0; k < CLS_IN; ++k) acc += p[k] * Wc1[k * CLS_HID + t];
    hh[t] = lrelu(acc);
    __syncthreads();
    if (t < N_CLASSES) {
        float a2 = bc2[t];
        for (int k = 0; k < CLS_HID; ++k) a2 += hh[k] * Wc2[k * N_CLASSES + t];
        out[g * N_CLASSES + t] = a2;
    }
}

extern "C" void kernel_launch(void* const* d_in, const int* in_sizes, int n_in,
                              void* d_out, int out_size, void* d_ws, size_t ws_size,
                              hipStream_t stream) {
    const int*   deg   = (const int*)d_in[0];
    const int*   edges = (const int*)d_in[1];
    const int*   srcv  = edges;
    const int*   dstv  = edges + N_EDGES;
    const int*   batch = (const int*)d_in[2];
    const float* epsv  = (const float*)d_in[3];
    const float* W1    = (const float*)d_in[4];
    const float* b1    = (const float*)d_in[5];
    const float* W2    = (const float*)d_in[6];
    const float* b2    = (const float*)d_in[7];
    const float* bn_g  = (const float*)d_in[8];
    const float* bn_b  = (const float*)d_in[9];
    const float* Wc1   = (const float*)d_in[10];
    const float* bc1   = (const float*)d_in[11];
    const float* Wc2   = (const float*)d_in[12];
    const float* bc2   = (const float*)d_in[13];

    char* ws = (char*)d_ws;
    const size_t BUFB = (size_t)N_NODES * DIM * 2;   // 25,600,000 B (bf16)
    size_t off = 0;
    ushort* buf0   = (ushort*)(ws + off); off += BUFB;
    ushort* buf1   = (ushort*)(ws + off); off += BUFB;
    ushort* W1t    = (ushort*)(ws + off); off += 4 * DIM * DIM * 2;
    ushort* W2t    = (ushort*)(ws + off); off += 4 * DIM * DIM * 2;
    float*  pooled = (float*)(ws + off);  off += N_GRAPHS * CLS_IN * 4;
    float*  statsA = (float*)(ws + off);  off += 4 * 2 * DIM * 4;
    uint*   cursor = (uint*)(ws + off);   off += (NBUCK + 8) * 4;
    uint*   base   = (uint*)(ws + off);   off += (NBUCK + 8) * 4;
    int*    indptr = (int*)(ws + off);    off += (N_NODES + 8) * 4;
    int*    csr    = (int*)(ws + off);    off += (size_t)N_EDGES * 4;
    uint*   ebuf   = (uint*)(ws + off);   off += (size_t)NBUCK * BUCK_CAP * 4;  // 12.8 MB

    k_convert_w<<<512, 256, 0, stream>>>(W1, W2, W1t, W2t, cursor, statsA, pooled);
    k_build_x<<<(N_NODES * 64 + 255) / 256, 256, 0, stream>>>(deg, batch, (uint*)buf0, pooled);
    k_partition<<<(N_EDGES + 16383) / 16384, 1024, 0, stream>>>(srcv, dstv, cursor, ebuf);
    k_bases<<<1, 1024, 0, stream>>>(cursor, base, indptr);
    k_sort<<<NBUCK, 512, 0, stream>>>(ebuf, cursor, base, csr, indptr);

    const int gemm_grid = (N_NODES + 127) / 128;   // 782
    const int agg_grid  = (N_NODES + 31) / 32;     // 3125
    for (int l = 0; l < N_LAYERS; ++l) {
        float* stats = statsA + l * 2 * DIM;
        k_agg6<<<agg_grid, 128, 0, stream>>>((const uint*)buf0, indptr, csr,
                                             (uint*)buf1, epsv, l);
        k_mlp<<<gemm_grid, 256, 0, stream>>>(buf1, W1t + l * DIM * DIM, b1 + l * DIM,
                                             W2t + l * DIM * DIM, b2 + l * DIM,
                                             buf1, stats);
        k_bnpool<<<(N_NODES + PROWS - 1) / PROWS, 256, 0, stream>>>(
            (const uint*)buf1, (uint*)buf0, stats, bn_g, bn_b, l, batch,
            pooled, DIM * (l + 1));
    }

    k_classifier<<<N_GRAPHS, 256, 0, stream>>>(pooled, Wc1, bc1, Wc2, bc2, (float*)d_out);
}